// Round 6
// baseline (477.365 us; speedup 1.0000x reference)
//
#include <hip/hip_runtime.h>
#include <hip/hip_cooperative_groups.h>
#include <stdint.h>

namespace cg = cooperative_groups;

// Problem constants
#define B_SZ   8192
#define IN_DIM 320      // S + A
#define H_DIM  1024
#define E_NUM  8
#define OUT_DIM 257     // S + 1
#define MAXT1  72       // TM=128 tile table (8192/128 + 8 experts)
#define MAXT2  136      // TM=64 tile table  (8192/64 + 8 experts)

typedef __bf16 bf16x8 __attribute__((ext_vector_type(8)));
typedef float  f32x4  __attribute__((ext_vector_type(4)));

typedef unsigned int __attribute__((address_space(1))) as1_uint;
typedef unsigned int __attribute__((address_space(3))) as3_uint;

__device__ __forceinline__ void gload_lds16(const void* g, void* l) {
    // async global->LDS, 16B/lane; LDS dest is wave-uniform base + lane*16
    __builtin_amdgcn_global_load_lds((const as1_uint*)g, (as3_uint*)l, 16, 0, 0);
}

__device__ __forceinline__ unsigned short f2bf(float f) {
    unsigned int u = __float_as_uint(f);
    return (unsigned short)((u + 0x7fffu + ((u >> 16) & 1u)) >> 16);  // RNE
}

// ---------------------------------------------------------------------------
// Grouped-GEMM tile (R4-verified body). TMxTN, 2-stage LDS dbuf, 4 waves in a
// 2x2 grid — wave (wm,wn) computes a (TM/2)x(TN/2) quadrant. LDS XOR-swizzle:
// slot (row, chunk c) holds global 16B chunk c ^ ((row>>1)&3) — 0 measured
// bank conflicts. Wt: (E, wtRows, K) bf16, N-major.
// MODE 0: Hout[(p0+m)*1024 + n] = bf16(relu(acc + bias))
// MODE 1 (layer 3 + fused reward): n<256 -> Out[row*256+n] = state + acc + b;
//         n==256 -> Out[B*256 + row] = acc + b;  n>256 -> discard.
template <int K, int TM, int TN, bool GATHER, int MODE>
__device__ __forceinline__ void gemm_tile(
    char* lds, int t, int ny,
    const unsigned short* __restrict__ Abase,
    const unsigned short* __restrict__ Wt, int wtRows,
    const float* __restrict__ bias, int bstride,
    unsigned short* __restrict__ Hout,
    float* __restrict__ Out, const float* __restrict__ state,
    const int* __restrict__ order,
    const int* __restrict__ te, const int* __restrict__ tp0,
    const int* __restrict__ tcnt) {
    constexpr int NI  = K / 32;
    constexpr int WM  = TM / 2, MF = WM / 16;
    constexpr int WN  = TN / 2, NF = WN / 16;
    constexpr int ABY = TM * 64;          // A stage bytes (TM rows x 64B)
    constexpr int BBY = TN * 64;          // B stage bytes
    constexpr int STG = ABY + BBY;        // 128x128: 16KB -> 2 stages = 32KB

    int cnt = tcnt[t];
    if (cnt == 0) return;
    int e = te[t], p0 = tp0[t];
    int n0 = ny * TN;
    int tid = threadIdx.x;
    int w = tid >> 6, lane = tid & 63;
    int wm = w >> 1, wn = w & 1;          // 2x2 wave grid

    // staging: thread fills LDS slot row=tid>>2 (+64 for 2nd A/B load), chunk
    // tid&3; fetches global chunk (tid&3) ^ swizzle(row);
    // swizzle(row)==swizzle(row+64).
    int r0 = tid >> 2;
    int cg2 = (tid & 3) ^ ((r0 >> 1) & 3);
    int rc0 = r0 < cnt ? r0 : cnt - 1;              // clamp; masked in epilogue
    long a0 = GATHER ? order[p0 + rc0] : (p0 + rc0);
    const unsigned short* aP0 = Abase + (size_t)a0 * K + cg2 * 8;
    const unsigned short* aP1 = aP0;
    if (TM == 128) {
        int rc1 = (r0 + 64) < cnt ? (r0 + 64) : cnt - 1;
        long a1 = GATHER ? order[p0 + rc1] : (p0 + rc1);
        aP1 = Abase + (size_t)a1 * K + cg2 * 8;
    }
    const unsigned short* bP0 = Wt + ((size_t)e * wtRows + ny * TN + r0) * K + cg2 * 8;
    const unsigned short* bP1 = bP0 + (size_t)64 * K;

    auto stage = [&](int k0s, int sb) {
        gload_lds16(aP0 + k0s, lds + sb + tid * 16);
        if (TM == 128)
            gload_lds16(aP1 + k0s, lds + sb + 4096 + tid * 16);
        gload_lds16(bP0 + k0s, lds + sb + ABY + tid * 16);
        if (TN == 128)
            gload_lds16(bP1 + k0s, lds + sb + ABY + 4096 + tid * 16);
    };

    f32x4 acc[MF][NF];
#pragma unroll
    for (int i = 0; i < MF; i++)
#pragma unroll
        for (int j = 0; j < NF; j++) acc[i][j] = (f32x4)0.f;

    const int fm   = lane & 15;
    const int kc   = lane >> 4;
    const int koff = ((kc ^ ((fm >> 1) & 3)) * 8);  // swizzled k-chunk offset

    stage(0, 0);
    for (int it = 0; it < NI; ++it) {
        __syncthreads();                 // drains tile-it loads (issued 1 iter ago)
        if (it + 1 < NI) stage((it + 1) * 32, ((it + 1) & 1) * STG);
        const unsigned short* Ls = (const unsigned short*)(lds + (it & 1) * STG);
        const unsigned short* As = Ls + wm * WM * 32;           // wave's WM-row A half
        const unsigned short* Bs = Ls + ABY / 2 + wn * WN * 32; // wave's WN-col B slice

        bf16x8 af[MF], bf[NF];
#pragma unroll
        for (int i = 0; i < MF; i++)
            af[i] = *(const bf16x8*)&As[(i * 16 + fm) * 32 + koff];
#pragma unroll
        for (int j = 0; j < NF; j++)
            bf[j] = *(const bf16x8*)&Bs[(j * 16 + fm) * 32 + koff];
#pragma unroll
        for (int i = 0; i < MF; i++)
#pragma unroll
            for (int j = 0; j < NF; j++)
                acc[i][j] = __builtin_amdgcn_mfma_f32_16x16x32_bf16(
                    af[i], bf[j], acc[i][j], 0, 0, 0);
    }
    // Inter-tile safety: last compute reads buffer (NI-1)&1 = 1 (NI even);
    // the next tile's stage(0,0) writes buffer 0 (disjoint), and its first
    // __syncthreads orders everything else. Epilogue reads only registers.

    // epilogue: C/D mapping col = lane&15, row = (lane>>4)*4 + reg
    int col = lane & 15, rq = lane >> 4;
#pragma unroll
    for (int j = 0; j < NF; j++) {
        int n = ny * TN + wn * WN + j * 16 + col;
        float bv = (MODE == 0) ? bias[e * bstride + n]
                               : ((n <= 256) ? bias[e * bstride + n] : 0.f);
#pragma unroll
        for (int i = 0; i < MF; i++) {
#pragma unroll
            for (int rr = 0; rr < 4; rr++) {
                int m = wm * WM + i * 16 + rq * 4 + rr;
                if (m < cnt) {
                    float v = acc[i][j][rr] + bv;
                    if (MODE == 0) {
                        Hout[(size_t)(p0 + m) * H_DIM + n] = f2bf(fmaxf(v, 0.f));
                    } else {
                        int row = order[p0 + m];
                        if (n < 256) {
                            size_t o = (size_t)row * 256 + n;
                            Out[o] = state[o] + v;
                        } else if (n == 256) {
                            Out[(size_t)B_SZ * 256 + row] = v;   // reward
                        }
                    }
                }
            }
        }
    }
}

// ---------------------------------------------------------------------------
// Prep work-items (shared by fused and fallback):
//  - bucket rows + build BOTH tile tables (block 0)
//  - x-concat/bf16 (items 0..2559)
//  - LDS transpose-convert 64x64 weight tiles (items 2560..5759)
//  - W3 reward column (items 5760..5791)
__device__ __forceinline__ void prep_bucket(
    char* smem, const int* __restrict__ idx, int* __restrict__ order,
    int* __restrict__ te1, int* __restrict__ tp1, int* __restrict__ tc1,
    int* __restrict__ te2, int* __restrict__ tp2, int* __restrict__ tc2) {
    int (*scnt)[E_NUM] = (int(*)[E_NUM])smem;
    int tid = threadIdx.x;
    int shard = tid & 15;
    if (tid < 128) ((int*)scnt)[tid] = 0;
    __syncthreads();
    for (int b = tid; b < B_SZ; b += 256) atomicAdd(&scnt[shard][idx[b]], 1);
    __syncthreads();
    if (tid == 0) {
        int pos = 0, t1 = 0, t2 = 0;
        for (int e = 0; e < E_NUM; e++) {
            int start = pos;
            for (int s = 0; s < 16; s++) { int c = scnt[s][e]; scnt[s][e] = pos; pos += c; }
            int tot = pos - start;
            for (int st = 0; st < tot; st += 128) {
                te1[t1] = e; tp1[t1] = start + st; tc1[t1] = min(128, tot - st); t1++;
            }
            for (int st = 0; st < tot; st += 64) {
                te2[t2] = e; tp2[t2] = start + st; tc2[t2] = min(64, tot - st); t2++;
            }
        }
        for (; t1 < MAXT1; t1++) { te1[t1] = 0; tp1[t1] = 0; tc1[t1] = 0; }
        for (; t2 < MAXT2; t2++) { te2[t2] = 0; tp2[t2] = 0; tc2[t2] = 0; }
    }
    __syncthreads();
    for (int b = tid; b < B_SZ; b += 256) {
        int e = idx[b];
        int p = atomicAdd(&scnt[shard][e], 1);
        order[p] = b;
    }
}

__device__ __forceinline__ void prep_item(
    char* smem, int item,
    const float* __restrict__ state, const float* __restrict__ action,
    const float* __restrict__ W1, const float* __restrict__ W2,
    const float* __restrict__ W3,
    unsigned short* __restrict__ xb, unsigned short* __restrict__ w1t,
    unsigned short* __restrict__ w2t, unsigned short* __restrict__ w3t) {
    int tid = threadIdx.x;
    if (item < 2560) {
        // x = concat(state, action) -> bf16
        int q = item * 256 + tid;   // quad id: b*80 + j
        int b = q / 80, j = q % 80;
        float4 v = (j < 64) ? ((const float4*)state)[b * 64 + j]
                            : ((const float4*)action)[b * 16 + (j - 64)];
        ushort4 o;
        o.x = f2bf(v.x); o.y = f2bf(v.y); o.z = f2bf(v.z); o.w = f2bf(v.w);
        ((ushort4*)xb)[q] = o;
    } else if (item < 5760) {
        // transpose-convert one 64x64 tile via padded LDS (verified R1 form)
        unsigned short (*tileU)[65] = (unsigned short(*)[65])smem;
        int it2 = item - 2560;
        int e, kt, nt, K, Nsrc, dstRows; bool vec;
        const float* src; unsigned short* dst;
        if (it2 < 640) {         // W1: (8,320,1024)->(8,1024,320)
            e = it2 / 80; int m = it2 % 80; kt = m / 16; nt = m % 16;
            K = IN_DIM; Nsrc = H_DIM; dstRows = H_DIM; src = W1; dst = w1t; vec = true;
        } else if (it2 < 2688) { // W2: (8,1024,1024)->(8,1024,1024)
            int r = it2 - 640; e = r / 256; int m = r % 256; kt = m / 16; nt = m % 16;
            K = H_DIM; Nsrc = H_DIM; dstRows = H_DIM; src = W2; dst = w2t; vec = true;
        } else {                 // W3: (8,1024,257)->rows 0..255 of (8,320,1024)
            int r = it2 - 2688; e = r / 64; int m = r % 64; kt = m / 4; nt = m % 4;
            K = H_DIM; Nsrc = OUT_DIM; dstRows = 320; src = W3; dst = w3t; vec = false;
        }
        int k0 = kt * 64, n0 = nt * 64;
        const float* s = src + (size_t)e * K * Nsrc;
        unsigned short* d = dst + (size_t)e * dstRows * K;
        int c4 = (tid & 15) * 4;
        int rb = tid >> 4;
#pragma unroll
        for (int p = 0; p < 4; p++) {
            int r = rb + p * 16;
            const float* sp = s + (size_t)(k0 + r) * Nsrc + n0 + c4;
            float4 v;
            if (vec) v = *(const float4*)sp;
            else { v.x = sp[0]; v.y = sp[1]; v.z = sp[2]; v.w = sp[3]; }
            tileU[r][c4 + 0] = f2bf(v.x);
            tileU[r][c4 + 1] = f2bf(v.y);
            tileU[r][c4 + 2] = f2bf(v.z);
            tileU[r][c4 + 3] = f2bf(v.w);
        }
        __syncthreads();
#pragma unroll
        for (int p = 0; p < 4; p++) {
            int n = rb + p * 16;
            ushort4 o;
            o.x = tileU[c4 + 0][n];
            o.y = tileU[c4 + 1][n];
            o.z = tileU[c4 + 2][n];
            o.w = tileU[c4 + 3][n];
            *(ushort4*)&d[(size_t)(n0 + n) * K + k0 + c4] = o;
        }
        __syncthreads();         // tileU reused by next item
    } else {
        // W3 reward column -> w3t row 256
        int i = (item - 5760) * 256 + tid;   // 8192 = 8e x 1024k
        int e = i >> 10, k = i & 1023;
        w3t[((size_t)e * 320 + 256) * H_DIM + k] =
            f2bf(W3[((size_t)e * H_DIM + k) * OUT_DIM + 256]);
    }
}

// ---------------------------------------------------------------------------
// Fused cooperative kernel: prep -> sync -> L1 -> sync -> L2 -> sync -> L3.
// Grid-stride everywhere -> correct for ANY grid size; host sizes the grid
// from the occupancy query (<=512 = 2 blocks/CU, safe under every accounting).
__global__ __launch_bounds__(256, 2)
void k_fused(const float* __restrict__ state, const float* __restrict__ action,
             const int* __restrict__ idx,
             const float* __restrict__ W1, const float* __restrict__ b1,
             const float* __restrict__ W2, const float* __restrict__ b2,
             const float* __restrict__ W3, const float* __restrict__ b3,
             float* __restrict__ out,
             unsigned short* __restrict__ xb, unsigned short* __restrict__ w1t,
             unsigned short* __restrict__ w2t, unsigned short* __restrict__ w3t,
             unsigned short* __restrict__ h1, unsigned short* __restrict__ h2,
             int* __restrict__ order,
             int* __restrict__ te1, int* __restrict__ tp1, int* __restrict__ tc1,
             int* __restrict__ te2, int* __restrict__ tp2, int* __restrict__ tc2) {
    __shared__ __align__(16) char smem[32768];
    cg::grid_group grid = cg::this_grid();
    int bid = blockIdx.x;
    int nb  = gridDim.x;

    // ===== phase 0: prep =====
    if (bid == 0) {
        prep_bucket(smem, idx, order, te1, tp1, tc1, te2, tp2, tc2);
    } else {
        for (int item = bid - 1; item < 5792; item += nb - 1)
            prep_item(smem, item, state, action, W1, W2, W3, xb, w1t, w2t, w3t);
    }

    __threadfence();
    grid.sync();

    // ===== layer 1: (B,320) x (320,1024), gather; 72x8 tiles of 128x128 =====
    for (int tl = bid; tl < MAXT1 * 8; tl += nb)
        gemm_tile<IN_DIM, 128, 128, true, 0>(smem, tl % MAXT1, tl / MAXT1,
            xb, w1t, H_DIM, b1, H_DIM, h1, nullptr, nullptr,
            order, te1, tp1, tc1);

    __threadfence();
    grid.sync();

    // ===== layer 2: (B,1024) x (1024,1024); 72x8 tiles of 128x128 =====
    for (int tl = bid; tl < MAXT1 * 8; tl += nb)
        gemm_tile<H_DIM, 128, 128, false, 0>(smem, tl % MAXT1, tl / MAXT1,
            h1, w2t, H_DIM, b2, H_DIM, h2, nullptr, nullptr,
            order, te1, tp1, tc1);

    __threadfence();
    grid.sync();

    // ===== layer 3 + reward: (B,1024) x (1024,320-pad); 136x5 of 64x64 =====
    for (int tl = bid; tl < MAXT2 * 5; tl += nb)
        gemm_tile<H_DIM, 64, 64, false, 1>(smem, tl % MAXT2, tl / MAXT2,
            h2, w3t, 320, b3, OUT_DIM, nullptr, out, state,
            order, te2, tp2, tc2);
}

// ---------------------------------------------------------------------------
// Fallback path (R4-proven multi-dispatch), used if cooperative launch fails.
__global__ __launch_bounds__(256)
void k_prep_fb(const float* __restrict__ state, const float* __restrict__ action,
               const int* __restrict__ idx,
               const float* __restrict__ W1, const float* __restrict__ W2,
               const float* __restrict__ W3,
               unsigned short* __restrict__ xb, unsigned short* __restrict__ w1t,
               unsigned short* __restrict__ w2t, unsigned short* __restrict__ w3t,
               int* __restrict__ order,
               int* __restrict__ te1, int* __restrict__ tp1, int* __restrict__ tc1,
               int* __restrict__ te2, int* __restrict__ tp2, int* __restrict__ tc2) {
    __shared__ __align__(16) char smem[8448];
    int bid = blockIdx.x;
    if (bid == 0)
        prep_bucket(smem, idx, order, te1, tp1, tc1, te2, tp2, tc2);
    else
        prep_item(smem, bid - 1, state, action, W1, W2, W3, xb, w1t, w2t, w3t);
}

template <int K, int TM, int TN, bool GATHER, int MODE>
__global__ __launch_bounds__(256, 2)
void k_gemm_fb(const unsigned short* __restrict__ Abase,
               const unsigned short* __restrict__ Wt, int wtRows,
               const float* __restrict__ bias, int bstride,
               unsigned short* __restrict__ Hout,
               float* __restrict__ Out, const float* __restrict__ state,
               const int* __restrict__ order,
               const int* __restrict__ te, const int* __restrict__ tp0,
               const int* __restrict__ tcnt) {
    __shared__ __align__(16) char lds[2 * (TM * 64 + TN * 64)];
    gemm_tile<K, TM, TN, GATHER, MODE>(lds, blockIdx.x, blockIdx.y,
        Abase, Wt, wtRows, bias, bstride, Hout, Out, state,
        order, te, tp0, tcnt);
}

// ---------------------------------------------------------------------------
extern "C" void kernel_launch(void* const* d_in, const int* in_sizes, int n_in,
                              void* d_out, int out_size, void* d_ws, size_t ws_size,
                              hipStream_t stream) {
    const float* state  = (const float*)d_in[0];
    const float* action = (const float*)d_in[1];
    const int*   idx    = (const int*)d_in[2];
    const float* W1     = (const float*)d_in[3];
    const float* b1     = (const float*)d_in[4];
    const float* W2     = (const float*)d_in[5];
    const float* b2     = (const float*)d_in[6];
    const float* W3     = (const float*)d_in[7];
    const float* b3     = (const float*)d_in[8];
    float* out = (float*)d_out;

    char* ws = (char*)d_ws;
    size_t off = 0;
    auto alloc = [&](size_t bytes) -> void* {
        void* p = ws + off;
        off = (off + bytes + 255) & ~(size_t)255;
        return p;
    };
    unsigned short* xb  = (unsigned short*)alloc((size_t)B_SZ * IN_DIM * 2);
    unsigned short* w1t = (unsigned short*)alloc((size_t)E_NUM * H_DIM * IN_DIM * 2);
    unsigned short* w2t = (unsigned short*)alloc((size_t)E_NUM * H_DIM * H_DIM * 2);
    unsigned short* w3t = (unsigned short*)alloc((size_t)E_NUM * 320 * H_DIM * 2);
    unsigned short* h1  = (unsigned short*)alloc((size_t)B_SZ * H_DIM * 2);
    unsigned short* h2  = (unsigned short*)alloc((size_t)B_SZ * H_DIM * 2);
    int* order = (int*)alloc(B_SZ * 4);
    int* te1   = (int*)alloc(MAXT1 * 4);
    int* tp1   = (int*)alloc(MAXT1 * 4);
    int* tc1   = (int*)alloc(MAXT1 * 4);
    int* te2   = (int*)alloc(MAXT2 * 4);
    int* tp2   = (int*)alloc(MAXT2 * 4);
    int* tc2   = (int*)alloc(MAXT2 * 4);

    // Size the cooperative grid from the runtime's own occupancy accounting,
    // capped at 2 blocks/CU (satisfiable under every LDS/VGPR interpretation).
    int perCU = 0;
    hipError_t qerr = hipOccupancyMaxActiveBlocksPerMultiprocessor(
        &perCU, (const void*)k_fused, 256, 0);
    int grid = 512;
    if (qerr == hipSuccess && perCU >= 1) {
        int cap = perCU * 256;           // 256 CUs on MI355X
        if (cap < grid) grid = cap;
    }

    void* args[] = {
        (void*)&state, (void*)&action, (void*)&idx,
        (void*)&W1, (void*)&b1, (void*)&W2, (void*)&b2, (void*)&W3, (void*)&b3,
        (void*)&out,
        (void*)&xb, (void*)&w1t, (void*)&w2t, (void*)&w3t,
        (void*)&h1, (void*)&h2,
        (void*)&order, (void*)&te1, (void*)&tp1, (void*)&tc1,
        (void*)&te2, (void*)&tp2, (void*)&tc2
    };
    hipError_t lerr = hipLaunchCooperativeKernel((const void*)k_fused,
                                                 dim3(grid), dim3(256),
                                                 args, 0, stream);
    if (lerr != hipSuccess) {
        // Fallback: proven multi-dispatch path (R4 configuration).
        k_prep_fb<<<5793, 256, 0, stream>>>(state, action, idx, W1, W2, W3,
                                            xb, w1t, w2t, w3t, order,
                                            te1, tp1, tc1, te2, tp2, tc2);
        k_gemm_fb<IN_DIM, 128, 128, true, 0><<<dim3(MAXT1, 8), 256, 0, stream>>>(
            xb, w1t, H_DIM, b1, H_DIM, h1, nullptr, nullptr, order, te1, tp1, tc1);
        k_gemm_fb<H_DIM, 128, 128, false, 0><<<dim3(MAXT1, 8), 256, 0, stream>>>(
            h1, w2t, H_DIM, b2, H_DIM, h2, nullptr, nullptr, order, te1, tp1, tc1);
        k_gemm_fb<H_DIM, 64, 64, false, 1><<<dim3(MAXT2, 5), 256, 0, stream>>>(
            h2, w3t, 320, b3, OUT_DIM, nullptr, out, state, order, te2, tp2, tc2);
    }
}

// Round 7
// 235.139 us; speedup vs baseline: 2.0301x; 2.0301x over previous
//
#include <hip/hip_runtime.h>
#include <stdint.h>

// Problem constants
#define B_SZ   8192
#define IN_DIM 320      // S + A
#define H_DIM  1024
#define E_NUM  8
#define OUT_DIM 257     // S + 1
#define MAXT1  72       // TM=128 tile table (8192/128 + 8 experts)
#define MAXT2  136      // TM=64 tile table  (8192/64 + 8 experts)

typedef __bf16 bf16x8 __attribute__((ext_vector_type(8)));
typedef float  f32x4  __attribute__((ext_vector_type(4)));

typedef unsigned int __attribute__((address_space(1))) as1_uint;
typedef unsigned int __attribute__((address_space(3))) as3_uint;

__device__ __forceinline__ void gload_lds16(const void* g, void* l) {
    // async global->LDS, 16B/lane; LDS dest is wave-uniform base + lane*16
    __builtin_amdgcn_global_load_lds((const as1_uint*)g, (as3_uint*)l, 16, 0, 0);
}

__device__ __forceinline__ unsigned short f2bf(float f) {
    unsigned int u = __float_as_uint(f);
    return (unsigned short)((u + 0x7fffu + ((u >> 16) & 1u)) >> 16);  // RNE
}

// ---------------------------------------------------------------------------
// Prep kernel, restructured for dispatch-rate (R0-R4 evidence: ~48us floor at
// 5793 workgroups regardless of inner work ~= CP dispatch rate). Now 1025
// fat blocks with per-block loops:
//   bid 0        : bucket + BOTH tile tables
//   1   .. 320   : x-concat/bf16, 8 items each (2560 items)
//   321 .. 448   : W1 transpose, 5 kt-tiles each (e,nt fixed)
//   449 .. 960   : W2 transpose, 4 kt-tiles each (e,nt,ktg fixed)
//   961 .. 992   : W3 transpose, 16 kt-tiles each (e,nt fixed)
//   993 .. 1024  : W3 reward column
// Transpose tile body is the verified R1 form: float4 loads -> bf16 ->
// padded LDS -> ushort4 stores.
__global__ __launch_bounds__(256)
void k_prep(const float* __restrict__ state, const float* __restrict__ action,
            const int* __restrict__ idx,
            const float* __restrict__ W1, const float* __restrict__ W2,
            const float* __restrict__ W3,
            unsigned short* __restrict__ xb, unsigned short* __restrict__ w1t,
            unsigned short* __restrict__ w2t, unsigned short* __restrict__ w3t,
            int* __restrict__ order,
            int* __restrict__ te1, int* __restrict__ tp1, int* __restrict__ tc1,
            int* __restrict__ te2, int* __restrict__ tp2, int* __restrict__ tc2) {
    __shared__ unsigned short tileU[64][65];
    __shared__ int scnt[16][E_NUM];
    int bid = blockIdx.x, tid = threadIdx.x;

    if (bid == 0) {
        // ---- bucket + tile tables ----
        int shard = tid & 15;
        if (tid < 128) ((int*)scnt)[tid] = 0;
        __syncthreads();
        for (int b = tid; b < B_SZ; b += 256) atomicAdd(&scnt[shard][idx[b]], 1);
        __syncthreads();
        if (tid == 0) {
            int pos = 0, t1 = 0, t2 = 0;
            for (int e = 0; e < E_NUM; e++) {
                int start = pos;
                for (int s = 0; s < 16; s++) { int c = scnt[s][e]; scnt[s][e] = pos; pos += c; }
                int tot = pos - start;
                for (int st = 0; st < tot; st += 128) {
                    te1[t1] = e; tp1[t1] = start + st; tc1[t1] = min(128, tot - st); t1++;
                }
                for (int st = 0; st < tot; st += 64) {
                    te2[t2] = e; tp2[t2] = start + st; tc2[t2] = min(64, tot - st); t2++;
                }
            }
            for (; t1 < MAXT1; t1++) { te1[t1] = 0; tp1[t1] = 0; tc1[t1] = 0; }
            for (; t2 < MAXT2; t2++) { te2[t2] = 0; tp2[t2] = 0; tc2[t2] = 0; }
        }
        __syncthreads();
        for (int b = tid; b < B_SZ; b += 256) {
            int e = idx[b];
            int p = atomicAdd(&scnt[shard][e], 1);
            order[p] = b;
        }
        return;
    }

    if (bid <= 320) {
        // ---- x = concat(state, action) -> bf16; 8 items per block ----
#pragma unroll
        for (int k = 0; k < 8; k++) {
            int q = ((bid - 1) * 8 + k) * 256 + tid;   // quad id: b*80 + j
            int b = q / 80, j = q % 80;
            float4 v = (j < 64) ? ((const float4*)state)[b * 64 + j]
                                : ((const float4*)action)[b * 16 + (j - 64)];
            ushort4 o;
            o.x = f2bf(v.x); o.y = f2bf(v.y); o.z = f2bf(v.z); o.w = f2bf(v.w);
            ((ushort4*)xb)[q] = o;
        }
        return;
    }

    if (bid <= 992) {
        // ---- transpose-convert, kt-looped ----
        int e, nt, kt0, nkt, K, Nsrc, dstRows; bool vec;
        const float* src; unsigned short* dst;
        if (bid <= 448) {        // W1: (8,320,1024)->(8,1024,320)
            int b = bid - 321; e = b >> 4; nt = b & 15;
            kt0 = 0; nkt = 5;
            K = IN_DIM; Nsrc = H_DIM; dstRows = H_DIM; src = W1; dst = w1t; vec = true;
        } else if (bid <= 960) { // W2: (8,1024,1024)->(8,1024,1024)
            int b = bid - 449; e = b >> 6; int r = b & 63;
            nt = r >> 2; kt0 = (r & 3) * 4; nkt = 4;
            K = H_DIM; Nsrc = H_DIM; dstRows = H_DIM; src = W2; dst = w2t; vec = true;
        } else {                 // W3: (8,1024,257)->rows 0..255 of (8,320,1024)
            int b = bid - 961; e = b >> 2; nt = b & 3;
            kt0 = 0; nkt = 16;
            K = H_DIM; Nsrc = OUT_DIM; dstRows = 320; src = W3; dst = w3t; vec = false;
        }
        const float* s = src + (size_t)e * K * Nsrc;
        unsigned short* d = dst + (size_t)e * dstRows * K;
        int c4 = (tid & 15) * 4;      // 4 consecutive cols per thread
        int rb = tid >> 4;            // 16 rows per pass
        int n0 = nt * 64;
        for (int kt = kt0; kt < kt0 + nkt; kt++) {
            int k0 = kt * 64;
            // phase 1: global (K-major) -> LDS, converting to bf16
#pragma unroll
            for (int p = 0; p < 4; p++) {
                int r = rb + p * 16;
                const float* sp = s + (size_t)(k0 + r) * Nsrc + n0 + c4;
                float4 v;
                if (vec) v = *(const float4*)sp;
                else { v.x = sp[0]; v.y = sp[1]; v.z = sp[2]; v.w = sp[3]; }
                tileU[r][c4 + 0] = f2bf(v.x);
                tileU[r][c4 + 1] = f2bf(v.y);
                tileU[r][c4 + 2] = f2bf(v.z);
                tileU[r][c4 + 3] = f2bf(v.w);
            }
            __syncthreads();
            // phase 2: LDS transposed read -> global (N-major), ushort4 stores
#pragma unroll
            for (int p = 0; p < 4; p++) {
                int n = rb + p * 16;
                ushort4 o;
                o.x = tileU[c4 + 0][n];
                o.y = tileU[c4 + 1][n];
                o.z = tileU[c4 + 2][n];
                o.w = tileU[c4 + 3][n];
                *(ushort4*)&d[(size_t)(n0 + n) * K + k0 + c4] = o;
            }
            __syncthreads();         // tileU reused next kt
        }
        return;
    }

    // ---- W3 reward column -> w3t row 256 ----  (32 blocks)
    int i = (bid - 993) * 256 + tid;         // 8192 = 8 experts x 1024 k
    int e = i >> 10, k = i & 1023;
    w3t[((size_t)e * 320 + 256) * H_DIM + k] =
        f2bf(W3[((size_t)e * H_DIM + k) * OUT_DIM + 256]);
}

// ---------------------------------------------------------------------------
// Grouped GEMM, TMxTN tile, BK=64 K-step (HALVES the per-iteration barrier
// drain count vs the proven BK=32 loop — the measured bottleneck: exposed
// memory latency per __syncthreads, 2.25 blocks/CU can't hide it).
// 2-stage LDS dbuf, 4 waves in a 2x2 grid, wave (wm,wn) owns (TM/2)x(TN/2).
// LDS XOR-swizzle over 8 chunks/row: slot (row, c) holds global 16B chunk
// c ^ (row&7); fragment read chunk = (4*ko + kc) ^ (row&7) -> <=2-way banks.
// SWAPXY: blockIdx.x = ny (gridDim.x = 8) so XCD = ny -> each XCD keeps its
// single 256KB B-panel L2-resident for the whole dispatch (T1 mechanism).
// Wt: (E, wtRows, K) bf16, N-major.
// MODE 0: Hout[(p0+m)*1024 + n] = bf16(relu(acc + bias))
// MODE 1 (layer 3 + fused reward): n<256 -> Out[row*256+n] = state + acc + b;
//         n==256 -> Out[B*256 + row] = acc + b;  n>256 -> discard.
template <int K, int TM, int TN, bool GATHER, int MODE, bool SWAPXY>
__global__ __launch_bounds__(256, 2)
void k_gemm(const unsigned short* __restrict__ Abase,
            const unsigned short* __restrict__ Wt, int wtRows,
            const float* __restrict__ bias, int bstride,
            unsigned short* __restrict__ Hout,
            float* __restrict__ Out, const float* __restrict__ state,
            const int* __restrict__ order,
            const int* __restrict__ te, const int* __restrict__ tp0,
            const int* __restrict__ tcnt) {
    constexpr int NI  = K / 64;
    constexpr int WM  = TM / 2, MF = WM / 16;
    constexpr int WN  = TN / 2, NF = WN / 16;
    constexpr int ABY = TM * 128;         // A stage bytes (TM rows x 128B)
    constexpr int BBY = TN * 128;         // B stage bytes
    constexpr int STG = ABY + BBY;        // 128x128: 32KB -> 2 stages = 64KB
    constexpr int AL  = TM / 32;          // A gload issues per stage
    constexpr int BL  = TN / 32;          // B gload issues per stage
    __shared__ __align__(16) char lds[2 * STG];

    int t  = SWAPXY ? blockIdx.y : blockIdx.x;
    int ny = SWAPXY ? blockIdx.x : blockIdx.y;
    int cnt = tcnt[t];
    if (cnt == 0) return;
    int e = te[t], p0 = tp0[t];
    int n0 = ny * TN;
    int tid = threadIdx.x;
    int w = tid >> 6, lane = tid & 63;
    int wm = w >> 1, wn = w & 1;          // 2x2 wave grid

    // staging: thread (r0 = tid>>3, c = tid&7) fills LDS slot (r0+32k, c);
    // fetches global chunk c ^ (r0&7). (row&7) invariant across k (32k%8==0).
    int r0 = tid >> 3;
    int c  = tid & 7;
    int cg2 = c ^ (r0 & 7);
    const unsigned short* aP[AL];
#pragma unroll
    for (int k = 0; k < AL; k++) {
        int r = r0 + 32 * k;
        int rc = r < cnt ? r : cnt - 1;             // clamp; masked in epilogue
        long ar = GATHER ? order[p0 + rc] : (p0 + rc);
        aP[k] = Abase + (size_t)ar * K + cg2 * 8;
    }
    const unsigned short* bP[BL];
#pragma unroll
    for (int k = 0; k < BL; k++)
        bP[k] = Wt + ((size_t)e * wtRows + n0 + r0 + 32 * k) * K + cg2 * 8;

    auto stage = [&](int k0s, int sb) {
#pragma unroll
        for (int k = 0; k < AL; k++)
            gload_lds16(aP[k] + k0s, lds + sb + tid * 16 + k * 4096);
#pragma unroll
        for (int k = 0; k < BL; k++)
            gload_lds16(bP[k] + k0s, lds + sb + ABY + tid * 16 + k * 4096);
    };

    f32x4 acc[MF][NF];
#pragma unroll
    for (int i = 0; i < MF; i++)
#pragma unroll
        for (int j = 0; j < NF; j++) acc[i][j] = (f32x4)0.f;

    const int fm = lane & 15;
    const int kc = lane >> 4;             // 0..3: which 8-elem chunk of 32-k

    stage(0, 0);
    for (int it = 0; it < NI; ++it) {
        __syncthreads();                  // drains tile-it loads (issued 1 iter ago)
        if (it + 1 < NI) stage((it + 1) * 64, ((it + 1) & 1) * STG);
        const unsigned short* Ls = (const unsigned short*)(lds + (it & 1) * STG);
        const unsigned short* As = Ls + wm * WM * 64;            // row stride 64 ushorts
        const unsigned short* Bs = Ls + ABY / 2 + wn * WN * 64;

#pragma unroll
        for (int ko = 0; ko < 2; ko++) {  // two 32-k MFMA sub-rounds per stage
            bf16x8 af[MF], bf[NF];
#pragma unroll
            for (int i = 0; i < MF; i++) {
                int ri = i * 16 + fm;
                int ce = (4 * ko + kc) ^ (ri & 7);
                af[i] = *(const bf16x8*)&As[ri * 64 + ce * 8];
            }
#pragma unroll
            for (int j = 0; j < NF; j++) {
                int rj = j * 16 + fm;
                int ce = (4 * ko + kc) ^ (rj & 7);
                bf[j] = *(const bf16x8*)&Bs[rj * 64 + ce * 8];
            }
#pragma unroll
            for (int i = 0; i < MF; i++)
#pragma unroll
                for (int j = 0; j < NF; j++)
                    acc[i][j] = __builtin_amdgcn_mfma_f32_16x16x32_bf16(
                        af[i], bf[j], acc[i][j], 0, 0, 0);
        }
    }

    // epilogue: C/D mapping col = lane&15, row = (lane>>4)*4 + reg
    int col = lane & 15, rq = lane >> 4;
#pragma unroll
    for (int j = 0; j < NF; j++) {
        int n = n0 + wn * WN + j * 16 + col;
        float bv = (MODE == 0) ? bias[e * bstride + n]
                               : ((n <= 256) ? bias[e * bstride + n] : 0.f);
#pragma unroll
        for (int i = 0; i < MF; i++) {
#pragma unroll
            for (int rr = 0; rr < 4; rr++) {
                int m = wm * WM + i * 16 + rq * 4 + rr;
                if (m < cnt) {
                    float v = acc[i][j][rr] + bv;
                    if (MODE == 0) {
                        Hout[(size_t)(p0 + m) * H_DIM + n] = f2bf(fmaxf(v, 0.f));
                    } else {
                        int row = order[p0 + m];
                        if (n < 256) {
                            size_t o = (size_t)row * 256 + n;
                            Out[o] = state[o] + v;
                        } else if (n == 256) {
                            Out[(size_t)B_SZ * 256 + row] = v;   // reward
                        }
                    }
                }
            }
        }
    }
}

// ---------------------------------------------------------------------------
extern "C" void kernel_launch(void* const* d_in, const int* in_sizes, int n_in,
                              void* d_out, int out_size, void* d_ws, size_t ws_size,
                              hipStream_t stream) {
    const float* state  = (const float*)d_in[0];
    const float* action = (const float*)d_in[1];
    const int*   idx    = (const int*)d_in[2];
    const float* W1     = (const float*)d_in[3];
    const float* b1     = (const float*)d_in[4];
    const float* W2     = (const float*)d_in[5];
    const float* b2     = (const float*)d_in[6];
    const float* W3     = (const float*)d_in[7];
    const float* b3     = (const float*)d_in[8];
    float* out = (float*)d_out;

    char* ws = (char*)d_ws;
    size_t off = 0;
    auto alloc = [&](size_t bytes) -> void* {
        void* p = ws + off;
        off = (off + bytes + 255) & ~(size_t)255;
        return p;
    };
    unsigned short* xb  = (unsigned short*)alloc((size_t)B_SZ * IN_DIM * 2);
    unsigned short* w1t = (unsigned short*)alloc((size_t)E_NUM * H_DIM * IN_DIM * 2);
    unsigned short* w2t = (unsigned short*)alloc((size_t)E_NUM * H_DIM * H_DIM * 2);
    unsigned short* w3t = (unsigned short*)alloc((size_t)E_NUM * 320 * H_DIM * 2);
    unsigned short* h1  = (unsigned short*)alloc((size_t)B_SZ * H_DIM * 2);
    unsigned short* h2  = (unsigned short*)alloc((size_t)B_SZ * H_DIM * 2);
    int* order = (int*)alloc(B_SZ * 4);
    int* te1   = (int*)alloc(MAXT1 * 4);
    int* tp1   = (int*)alloc(MAXT1 * 4);
    int* tc1   = (int*)alloc(MAXT1 * 4);
    int* te2   = (int*)alloc(MAXT2 * 4);
    int* tp2   = (int*)alloc(MAXT2 * 4);
    int* tc2   = (int*)alloc(MAXT2 * 4);

    // prep: 1025 fat blocks (was 5793 — dispatch-rate floor)
    k_prep<<<1025, 256, 0, stream>>>(state, action, idx, W1, W2, W3,
                                     xb, w1t, w2t, w3t, order,
                                     te1, tp1, tc1, te2, tp2, tc2);

    // layer 1: (B,320) x (320,1024), gather; 8 x 72 grid (XCD = ny)
    k_gemm<IN_DIM, 128, 128, true, 0, true><<<dim3(8, MAXT1), 256, 0, stream>>>(
        xb, w1t, H_DIM, b1, H_DIM, h1, nullptr, nullptr, order, te1, tp1, tc1);
    // layer 2: (B,1024) x (1024,1024); 8 x 72 grid (XCD = ny)
    k_gemm<H_DIM, 128, 128, false, 0, true><<<dim3(8, MAXT1), 256, 0, stream>>>(
        h1, w2t, H_DIM, b2, H_DIM, h2, nullptr, nullptr, order, te1, tp1, tc1);
    // layer 3 + fused reward: (B,1024) x (1024,320-pad); 136 x 5 (XCD = t%8)
    k_gemm<H_DIM, 64, 64, false, 1, false><<<dim3(MAXT2, 5), 256, 0, stream>>>(
        h2, w3t, 320, b3, OUT_DIM, nullptr, out, state, order, te2, tp2, tc2);
}